// Round 4
// baseline (770.303 us; speedup 1.0000x reference)
//
#include <hip/hip_runtime.h>
#include <stdint.h>

// B=8, Lt=64, Lv=16384, D=256. Input dtype detected at runtime (bf16 vs fp32).
#define NB 8
#define LT 64
#define LV 16384
#define DD 256
#define EPSV 1e-6f
#define FMAXV 3.4028234663852886e38f

typedef unsigned short u16t;

__device__ __forceinline__ float bf2f(u16t h) {
    union { uint32_t u; float f; } cv; cv.u = ((uint32_t)h) << 16; return cv.f;
}
__device__ __forceinline__ u16t f2bf(float f) {
    union { float f; uint32_t u; } cv; cv.f = f;
    uint32_t u = cv.u;
    return (u16t)((u + 0x7fffu + ((u >> 16) & 1u)) >> 16);  // RNE, finite
}
__device__ __forceinline__ float fixnum(float f) {
    if (f != f) return 0.0f;
    if (f > FMAXV) return FMAXV;
    if (f < -FMAXV) return -FMAXV;
    return f;
}
__device__ __forceinline__ float load_in(const void* p, long i, int isf32) {
    return isf32 ? ((const float*)p)[i] : bf2f(((const u16t*)p)[i]);
}
__device__ __forceinline__ float lanebcast(float v, int k) {
    union { float f; int i; } cv; cv.f = v;
    union { int i; float f; } cb; cb.i = __builtin_amdgcn_readlane(cv.i, k);
    return cb.f;
}

// Canary: fill d_out (as u16, conservative size) with bf16 0.25. If the final
// result is still exactly the memset-0 baseline (err .664), our code never ran.
__global__ void k_canary(u16t* out, int n) {
    int i = blockIdx.x * 256 + threadIdx.x;
    if (i < n) out[i] = (u16t)0x3E80;
}

// Sentinel: bf16 1.0 (err ~1.0 -> "ws too small" signature)
__global__ void k_sentinel(u16t* out, int n) {
    int i = blockIdx.x * 256 + threadIdx.x;
    if (i < n) out[i] = (u16t)0x3F80;
}

// Dtype sniffer: examine first 1024 u16 words of v. bf16 data -> nearly all
// words have a sane exponent; fp32 data -> mantissa-half words are junk.
__global__ void k_sniff(const u16t* v, int* flag) {
    int lane = threadIdx.x;  // 64 threads
    int sane = 0;
    for (int i = 0; i < 16; ++i) {
        u16t h = v[lane * 16 + i];
        int ex = (h >> 7) & 0xFF;
        if ((h & 0x7FFF) == 0 || (ex >= 96 && ex < 160)) ++sane;
    }
    #pragma unroll
    for (int o = 1; o < 64; o <<= 1) sane += __shfl_xor(sane, o, 64);
    if (lane == 0) flag[0] = (sane < 900) ? 1 : 0;  // 1 = fp32 inputs
}

// zero Z,S1,S2 (1536 floats)
__global__ void k0_zero(float* Z) {
    int i = blockIdx.x * 256 + threadIdx.x;
    if (i < 1536) Z[i] = 0.0f;
}

// tnT[b][k][r] = bf16( l2norm(nan_to_num(t[b][r][:]))[k] * 0.5 ). Block per row.
__global__ void k1_tnorm(const void* t, u16t* tnT, const int* flag) {
    __shared__ float red[256];
    int isf32 = flag[0];
    int row = blockIdx.x;                 // b*64 + r
    int b = row >> 6, r = row & 63;
    int k = threadIdx.x;
    float x = fixnum(load_in(t, (long)row * DD + k, isf32));
    red[k] = x * x;
    __syncthreads();
    for (int s = 128; s > 0; s >>= 1) {
        if (k < s) red[k] += red[k + s];
        __syncthreads();
    }
    float scale = 0.5f / fmaxf(sqrtf(red[0]), EPSV);
    tnT[b * (DD * LT) + k * LT + r] = f2bf(x * scale);
}

// Core: 16 consecutive v-rows -> e[r] = exp((v_r . tn_t)/||v_r||) at t = lane.
__device__ __forceinline__ void wave_rows16(const void* v, const u16t* tnTb,
                                            long rowbase, int lane, int isf32,
                                            float* eout) {
    float Sacc[16], ssqp[16];
    #pragma unroll
    for (int r = 0; r < 16; ++r) { Sacc[r] = 0.f; ssqp[r] = 0.f; }
    for (int c = 0; c < 4; ++c) {
        float tn_reg[64];
        #pragma unroll
        for (int k = 0; k < 64; ++k)
            tn_reg[k] = bf2f(tnTb[(c * 64 + k) * LT + lane]);
        #pragma unroll
        for (int r = 0; r < 16; ++r) {
            float vv = fixnum(load_in(v, (rowbase + r) * DD + c * 64 + lane, isf32));
            ssqp[r] += vv * vv;
            #pragma unroll
            for (int k = 0; k < 64; ++k)
                Sacc[r] = fmaf(lanebcast(vv, k), tn_reg[k], Sacc[r]);
        }
    }
    #pragma unroll
    for (int r = 0; r < 16; ++r) {
        float ss = ssqp[r];
        #pragma unroll
        for (int o = 1; o < 64; o <<= 1) ss += __shfl_xor(ss, o, 64);
        float fac = 1.0f / fmaxf(sqrtf(ss), EPSV);
        eout[r] = __expf(Sacc[r] * fac);   // S in [-0.5,0.5]
    }
}

// Pass 1: Z[t] += sum_v e ; S1[t] += sum_v exp(A/2) ; S2[t] += sum_v exp(A/2)*A
__global__ __launch_bounds__(256) void k2_acc(const void* v, const u16t* tnT,
                                              float* Z, float* S1, float* S2,
                                              const int* flag) {
    __shared__ float rbuf[3][256];
    int isf32 = flag[0];
    int tid = threadIdx.x, wave = tid >> 6, lane = tid & 63;
    int b = blockIdx.y, tile = blockIdx.x;
    long rowbase = (long)b * LV + tile * 64 + wave * 16;
    const u16t* tnTb = tnT + b * (DD * LT);
    float e[16];
    wave_rows16(v, tnTb, rowbase, lane, isf32, e);
    float accZ = 0.f, accS1 = 0.f, accS2 = 0.f;
    #pragma unroll
    for (int r = 0; r < 16; ++r) {
        float se = e[r];
        #pragma unroll
        for (int o = 1; o < 64; o <<= 1) se += __shfl_xor(se, o, 64);
        float A = e[r] / se;
        float w = __expf(0.5f * A);
        accZ += e[r]; accS1 += w; accS2 += w * A;
    }
    rbuf[0][tid] = accZ; rbuf[1][tid] = accS1; rbuf[2][tid] = accS2;
    __syncthreads();
    if (tid < 64) {
        float z  = rbuf[0][tid] + rbuf[0][tid+64] + rbuf[0][tid+128] + rbuf[0][tid+192];
        float a  = rbuf[1][tid] + rbuf[1][tid+64] + rbuf[1][tid+128] + rbuf[1][tid+192];
        float s2 = rbuf[2][tid] + rbuf[2][tid+64] + rbuf[2][tid+128] + rbuf[2][tid+192];
        atomicAdd(&Z[b * LT + tid], z);
        atomicAdd(&S1[b * LT + tid], a);
        atomicAdd(&S2[b * LT + tid], s2);
    }
}

// c[t] = (S2/S1) / ((sum_t S2/S1 + eps) * Z[t])
__global__ __launch_bounds__(64) void k3_coef(const float* Z, const float* S1,
                                              const float* S2, float* c) {
    int b = blockIdx.x, lane = threadIdx.x;
    float ts = S2[b * LT + lane] / S1[b * LT + lane];
    float tot = ts;
    #pragma unroll
    for (int o = 1; o < 64; o <<= 1) tot += __shfl_xor(tot, o, 64);
    c[b * LT + lane] = ts / ((tot + EPSV) * Z[b * LT + lane]);
}

// Pass 2: scores[row] = sum_t e[row,t] * c[t]
__global__ __launch_bounds__(256) void k2_score(const void* v, const u16t* tnT,
                                                const float* c, float* scores,
                                                const int* flag) {
    int isf32 = flag[0];
    int tid = threadIdx.x, wave = tid >> 6, lane = tid & 63;
    int b = blockIdx.y, tile = blockIdx.x;
    long rowbase = (long)b * LV + tile * 64 + wave * 16;
    const u16t* tnTb = tnT + b * (DD * LT);
    float cr = c[b * LT + lane];
    float e[16];
    wave_rows16(v, tnTb, rowbase, lane, isf32, e);
    #pragma unroll
    for (int r = 0; r < 16; ++r) {
        float x = e[r] * cr;
        #pragma unroll
        for (int o = 1; o < 64; o <<= 1) x += __shfl_xor(x, o, 64);
        if (lane == 0) scores[rowbase + r] = x;
    }
}

// Deterministic per-b min/max
__global__ __launch_bounds__(256) void k_mnmx(const float* scores, float* mnmx) {
    __shared__ float rmn[256], rmx[256];
    int b = blockIdx.x, tid = threadIdx.x;
    float mn = FMAXV, mx = -FMAXV;
    for (int i = tid; i < LV; i += 256) {
        float x = scores[b * LV + i];
        mn = fminf(mn, x); mx = fmaxf(mx, x);
    }
    rmn[tid] = mn; rmx[tid] = mx;
    __syncthreads();
    for (int s = 128; s > 0; s >>= 1) {
        if (tid < s) {
            rmn[tid] = fminf(rmn[tid], rmn[tid + s]);
            rmx[tid] = fmaxf(rmx[tid], rmx[tid + s]);
        }
        __syncthreads();
    }
    if (tid == 0) { mnmx[b * 2] = rmn[0]; mnmx[b * 2 + 1] = rmx[0]; }
}

// out = (scores - mn)/(mx - mn + eps); dtype per flag
__global__ __launch_bounds__(256) void k5_out(const float* scores, const float* mnmx,
                                              void* out, const int* flag) {
    int isf32 = flag[0];
    int i = blockIdx.x * 256 + threadIdx.x;
    if (i >= NB * LV) return;
    int b = i >> 14;
    float mn = mnmx[b * 2], mx = mnmx[b * 2 + 1];
    float val = (scores[i] - mn) / (mx - mn + EPSV);
    if (isf32) ((float*)out)[i] = val;
    else ((u16t*)out)[i] = f2bf(val);
}

extern "C" void kernel_launch(void* const* d_in, const int* in_sizes, int n_in,
                              void* d_out, int out_size, void* d_ws, size_t ws_size,
                              hipStream_t stream) {
    const void* t = d_in[0];   // [8,64,256]
    const void* v = d_in[1];   // [8,16384,256]
    char* w = (char*)d_ws;

    u16t*  tnT    = (u16t*)w;                 // 262144 B
    float* scores = (float*)(w + 262144);     // 524288 B
    float* Z      = (float*)(w + 786432);
    float* S1     = Z + 512;
    float* S2     = Z + 1024;
    float* c      = Z + 1536;
    float* mnmx   = Z + 2048;                 // 16 floats
    int*   flag   = (int*)(Z + 2064);
    const size_t NEED = 786432 + 2068 * 4;

    int n_out = out_size;                      // 131072
    k_canary<<<(n_out + 255) / 256, 256, 0, stream>>>((u16t*)d_out, n_out);

    if (d_ws == nullptr || ws_size < NEED) {
        k_sentinel<<<(n_out + 255) / 256, 256, 0, stream>>>((u16t*)d_out, n_out);
        return;
    }
    k_sniff<<<1, 64, 0, stream>>>((const u16t*)v, flag);
    k0_zero<<<6, 256, 0, stream>>>(Z);
    k1_tnorm<<<512, 256, 0, stream>>>(t, tnT, flag);
    k2_acc<<<dim3(256, NB), 256, 0, stream>>>(v, tnT, Z, S1, S2, flag);
    k3_coef<<<NB, 64, 0, stream>>>(Z, S1, S2, c);
    k2_score<<<dim3(256, NB), 256, 0, stream>>>(v, tnT, c, scores, flag);
    k_mnmx<<<NB, 256, 0, stream>>>(scores, mnmx);
    k5_out<<<512, 256, 0, stream>>>(scores, mnmx, d_out, flag);
}

// Round 6
// 266.235 us; speedup vs baseline: 2.8933x; 2.8933x over previous
//
#include <hip/hip_runtime.h>
#include <stdint.h>

// B=8, Lt=64, Lv=16384, D=256. Inputs fp32 (runtime-sniffed; R4-proven), out per flag.
#define NB 8
#define LT 64
#define LV 16384
#define DD 256
#define EPSV 1e-6f
#define BF16MAX 3.3895313892515355e38f

typedef unsigned short u16t;
typedef __attribute__((ext_vector_type(8))) short short8;
typedef __attribute__((ext_vector_type(4))) float floatx4;

__device__ __forceinline__ float bf2f(u16t h) {
    union { uint32_t u; float f; } cv; cv.u = ((uint32_t)h) << 16; return cv.f;
}
__device__ __forceinline__ uint32_t asu(float f) { union { float f; uint32_t u; } c; c.f = f; return c.u; }
__device__ __forceinline__ float asf(uint32_t u) { union { uint32_t u; float f; } c; c.u = u; return c.f; }
__device__ __forceinline__ u16t f2bf(float f) {
    uint32_t u = asu(f);
    return (u16t)((u + 0x7fffu + ((u >> 16) & 1u)) >> 16);  // RNE, finite
}
__device__ __forceinline__ float fixnum(float f) {
    if (f != f) return 0.0f;
    if (f > BF16MAX) return BF16MAX;    // clamp so RNE-to-bf16 can't hit inf
    if (f < -BF16MAX) return -BF16MAX;
    return f;
}
__device__ __forceinline__ float load_in(const void* p, long i, int isf32) {
    return isf32 ? ((const float*)p)[i] : bf2f(((const u16t*)p)[i]);
}
// RNE bf16 head; returns bits, sets float value. Residual a - hf is exact (Sterbenz).
__device__ __forceinline__ uint32_t bfhead(float a, float& hf) {
    uint32_t u = asu(a);
    uint32_t h = (u + 0x7fffu + ((u >> 16) & 1u)) >> 16;
    hf = asf(h << 16);
    return h;
}

// Dtype sniffer (R4-proven): bf16 data -> ~all sane exponents; fp32 -> ~60%.
__global__ void k_sniff(const u16t* v, int* flag) {
    int lane = threadIdx.x;
    int sane = 0;
    for (int i = 0; i < 16; ++i) {
        u16t h = v[lane * 16 + i];
        int ex = (h >> 7) & 0xFF;
        if ((h & 0x7FFF) == 0 || (ex >= 96 && ex < 160)) ++sane;
    }
    #pragma unroll
    for (int o = 1; o < 64; o <<= 1) sane += __shfl_xor(sane, o, 64);
    if (lane == 0) flag[0] = (sane < 900) ? 1 : 0;  // 1 = fp32
}

__global__ void k0_zero(float* Z) {
    int i = blockIdx.x * 256 + threadIdx.x;
    if (i < 1536) Z[i] = 0.0f;
}

// tnB[b][t][k] = bf16( l2norm(nan_to_num(t_row)) * 0.5 ), row-major (k contiguous).
__global__ void k1_tnorm(const void* t, u16t* tnB, const int* flag) {
    __shared__ float red[256];
    int isf32 = flag[0];
    int row = blockIdx.x;                 // b*64 + r
    int k = threadIdx.x;
    float x = fixnum(load_in(t, (long)row * DD + k, isf32));
    red[k] = x * x;
    __syncthreads();
    for (int s = 128; s > 0; s >>= 1) {
        if (k < s) red[k] += red[k + s];
        __syncthreads();
    }
    float scale = 0.5f / fmaxf(sqrtf(red[0]), EPSV);
    tnB[row * DD + k] = f2bf(x * scale);
}

// MFMA GEMM + fused softmax stats / scores.
// Per wave: 32 v-rows x 64 t, K=256. A = v as EXACT 3-term RNE bf16 split
// (h1+h2+h3 reproduces fp32 to <2^-27 rel), B = tn bf16 (R4-parity).
// mode 0: Z[t]=sum e, S1[t]=sum exp(A/2), S2[t]=sum exp(A/2)*A
// mode 1: scores[row] = sum_t e * c[t]
__global__ __launch_bounds__(256) void k_gemm(const void* v, const u16t* tnB,
                                              float* Z, float* S1, float* S2,
                                              const float* c, float* scores,
                                              const int* flag, int mode) {
    __shared__ u16t ldsT[64 * 264];        // [t][k], +8 pad per row (33 KB)
    __shared__ float zlds[3][4][64];       // block reduction (3 KB)
    int isf32 = flag[0];
    int tid = threadIdx.x, wave = tid >> 6, lane = tid & 63;
    int c16 = lane & 15, q = lane >> 4;
    int b = blockIdx.y, tile = blockIdx.x;
    int rowbase = tile * 128 + wave * 32;  // within b

    {   // stage tn[b] into LDS (64 x 256 u16, padded rows)
        const u16t* src = tnB + (size_t)b * (LT * DD);
        for (int i = tid; i < 2048; i += 256) {
            int tt = i >> 5, k8 = i & 31;
            *(uint4*)&ldsT[tt * 264 + k8 * 8] = *(const uint4*)&src[tt * DD + k8 * 8];
        }
    }
    __syncthreads();

    floatx4 acc[2][4];                     // [mt][nt]
    #pragma unroll
    for (int mt = 0; mt < 2; ++mt)
        #pragma unroll
        for (int nt = 0; nt < 4; ++nt) acc[mt][nt] = (floatx4){0.f, 0.f, 0.f, 0.f};
    float ssqp[2] = {0.f, 0.f};

    for (int kc = 0; kc < 8; ++kc) {
        short8 bf[4];                      // B: tn[t=nt*16+c16][k=kc*32+q*8 ..]
        #pragma unroll
        for (int nt = 0; nt < 4; ++nt)
            bf[nt] = *(const short8*)&ldsT[(nt * 16 + c16) * 264 + kc * 32 + q * 8];

        #pragma unroll
        for (int mt = 0; mt < 2; ++mt) {
            int row = rowbase + mt * 16 + c16;
            float f[8];
            if (isf32) {
                const float* vr = (const float*)v +
                    ((size_t)b * LV + row) * DD + kc * 32 + q * 8;
                float4 p0 = *(const float4*)vr;
                float4 p1 = *(const float4*)(vr + 4);
                f[0]=p0.x; f[1]=p0.y; f[2]=p0.z; f[3]=p0.w;
                f[4]=p1.x; f[5]=p1.y; f[6]=p1.z; f[7]=p1.w;
            } else {
                const u16t* vr = (const u16t*)v +
                    ((size_t)b * LV + row) * DD + kc * 32 + q * 8;
                uint4 u = *(const uint4*)vr;
                f[0]=bf2f((u16t)u.x); f[1]=bf2f((u16t)(u.x>>16));
                f[2]=bf2f((u16t)u.y); f[3]=bf2f((u16t)(u.y>>16));
                f[4]=bf2f((u16t)u.z); f[5]=bf2f((u16t)(u.z>>16));
                f[6]=bf2f((u16t)u.w); f[7]=bf2f((u16t)(u.w>>16));
            }
            #pragma unroll
            for (int i = 0; i < 8; ++i) f[i] = fixnum(f[i]);
            // exact 3-term RNE split: f = h1 + h2 + h3 (to <2^-27 rel)
            union { short8 s; uint32_t u[4]; } a1, a2, a3;
            #pragma unroll
            for (int i = 0; i < 4; ++i) {
                float e0 = f[2*i], e1 = f[2*i+1];
                ssqp[mt] += e0 * e0 + e1 * e1;
                float h10f, h11f, h20f, h21f, dummy;
                uint32_t h10 = bfhead(e0, h10f), h11 = bfhead(e1, h11f);
                float r10 = e0 - h10f,  r11 = e1 - h11f;
                uint32_t h20 = bfhead(r10, h20f), h21 = bfhead(r11, h21f);
                float r20 = r10 - h20f, r21 = r11 - h21f;
                uint32_t h30 = bfhead(r20, dummy), h31 = bfhead(r21, dummy);
                a1.u[i] = h10 | (h11 << 16);
                a2.u[i] = h20 | (h21 << 16);
                a3.u[i] = h30 | (h31 << 16);
            }
            #pragma unroll
            for (int nt = 0; nt < 4; ++nt) {
                acc[mt][nt] = __builtin_amdgcn_mfma_f32_16x16x32_bf16(
                    a1.s, bf[nt], acc[mt][nt], 0, 0, 0);
                acc[mt][nt] = __builtin_amdgcn_mfma_f32_16x16x32_bf16(
                    a2.s, bf[nt], acc[mt][nt], 0, 0, 0);
                acc[mt][nt] = __builtin_amdgcn_mfma_f32_16x16x32_bf16(
                    a3.s, bf[nt], acc[mt][nt], 0, 0, 0);
            }
        }
    }

    // full ||v||^2 per row (row = rowbase + mt*16 + c16 at this lane)
    float ssqf[2];
    #pragma unroll
    for (int mt = 0; mt < 2; ++mt) {
        float s = ssqp[mt];
        s += __shfl_xor(s, 16, 64);
        s += __shfl_xor(s, 32, 64);
        ssqf[mt] = s;
    }
    // fac for this lane's D rows: D row = q*4+reg -> source lane q*4+reg (c16=row)
    float facr[2][4];
    #pragma unroll
    for (int mt = 0; mt < 2; ++mt)
        #pragma unroll
        for (int reg = 0; reg < 4; ++reg) {
            float ss = __shfl(ssqf[mt], q * 4 + reg, 64);
            facr[mt][reg] = 1.0f / fmaxf(sqrtf(ss), EPSV);
        }

    if (mode == 0) {
        float zacc[4] = {0,0,0,0}, s1acc[4] = {0,0,0,0}, s2acc[4] = {0,0,0,0};
        #pragma unroll
        for (int mt = 0; mt < 2; ++mt)
            #pragma unroll
            for (int reg = 0; reg < 4; ++reg) {
                float e[4], se = 0.f;
                #pragma unroll
                for (int nt = 0; nt < 4; ++nt) {
                    e[nt] = __expf(acc[mt][nt][reg] * facr[mt][reg]);
                    se += e[nt];
                }
                se += __shfl_xor(se, 1, 64);
                se += __shfl_xor(se, 2, 64);
                se += __shfl_xor(se, 4, 64);
                se += __shfl_xor(se, 8, 64);
                float inv = 1.0f / se;
                #pragma unroll
                for (int nt = 0; nt < 4; ++nt) {
                    float A = e[nt] * inv;
                    float w = __expf(0.5f * A);
                    zacc[nt] += e[nt]; s1acc[nt] += w; s2acc[nt] += w * A;
                }
            }
        #pragma unroll
        for (int nt = 0; nt < 4; ++nt) {
            zacc[nt]  += __shfl_xor(zacc[nt], 16, 64);  zacc[nt]  += __shfl_xor(zacc[nt], 32, 64);
            s1acc[nt] += __shfl_xor(s1acc[nt], 16, 64); s1acc[nt] += __shfl_xor(s1acc[nt], 32, 64);
            s2acc[nt] += __shfl_xor(s2acc[nt], 16, 64); s2acc[nt] += __shfl_xor(s2acc[nt], 32, 64);
        }
        if (lane < 16) {
            #pragma unroll
            for (int nt = 0; nt < 4; ++nt) {
                zlds[0][wave][nt * 16 + lane] = zacc[nt];
                zlds[1][wave][nt * 16 + lane] = s1acc[nt];
                zlds[2][wave][nt * 16 + lane] = s2acc[nt];
            }
        }
        __syncthreads();
        if (tid < 64) {
            float z  = zlds[0][0][tid] + zlds[0][1][tid] + zlds[0][2][tid] + zlds[0][3][tid];
            float a  = zlds[1][0][tid] + zlds[1][1][tid] + zlds[1][2][tid] + zlds[1][3][tid];
            float s2 = zlds[2][0][tid] + zlds[2][1][tid] + zlds[2][2][tid] + zlds[2][3][tid];
            atomicAdd(&Z[b * LT + tid], z);
            atomicAdd(&S1[b * LT + tid], a);
            atomicAdd(&S2[b * LT + tid], s2);
        }
    } else {
        float cc[4];
        #pragma unroll
        for (int nt = 0; nt < 4; ++nt) cc[nt] = c[b * LT + nt * 16 + c16];
        #pragma unroll
        for (int mt = 0; mt < 2; ++mt)
            #pragma unroll
            for (int reg = 0; reg < 4; ++reg) {
                float x = 0.f;
                #pragma unroll
                for (int nt = 0; nt < 4; ++nt)
                    x += __expf(acc[mt][nt][reg] * facr[mt][reg]) * cc[nt];
                x += __shfl_xor(x, 1, 64);
                x += __shfl_xor(x, 2, 64);
                x += __shfl_xor(x, 4, 64);
                x += __shfl_xor(x, 8, 64);
                if (c16 == 0)
                    scores[(size_t)b * LV + rowbase + mt * 16 + q * 4 + reg] = x;
            }
    }
}

// c[t] = (S2/S1) / ((sum_t S2/S1 + eps) * Z[t])
__global__ __launch_bounds__(64) void k3_coef(const float* Z, const float* S1,
                                              const float* S2, float* c) {
    int b = blockIdx.x, lane = threadIdx.x;
    float ts = S2[b * LT + lane] / S1[b * LT + lane];
    float tot = ts;
    #pragma unroll
    for (int o = 1; o < 64; o <<= 1) tot += __shfl_xor(tot, o, 64);
    c[b * LT + lane] = ts / ((tot + EPSV) * Z[b * LT + lane]);
}

__global__ __launch_bounds__(256) void k_mnmx(const float* scores, float* mnmx) {
    __shared__ float rmn[256], rmx[256];
    int b = blockIdx.x, tid = threadIdx.x;
    float mn = 3.4e38f, mx = -3.4e38f;
    for (int i = tid; i < LV; i += 256) {
        float x = scores[b * LV + i];
        mn = fminf(mn, x); mx = fmaxf(mx, x);
    }
    rmn[tid] = mn; rmx[tid] = mx;
    __syncthreads();
    for (int s = 128; s > 0; s >>= 1) {
        if (tid < s) {
            rmn[tid] = fminf(rmn[tid], rmn[tid + s]);
            rmx[tid] = fmaxf(rmx[tid], rmx[tid + s]);
        }
        __syncthreads();
    }
    if (tid == 0) { mnmx[b * 2] = rmn[0]; mnmx[b * 2 + 1] = rmx[0]; }
}

__global__ __launch_bounds__(256) void k5_out(const float* scores, const float* mnmx,
                                              void* out, const int* flag) {
    int isf32 = flag[0];
    int i = blockIdx.x * 256 + threadIdx.x;
    if (i >= NB * LV) return;
    int b = i >> 14;
    float mn = mnmx[b * 2], mx = mnmx[b * 2 + 1];
    float val = (scores[i] - mn) / (mx - mn + EPSV);
    if (isf32) ((float*)out)[i] = val;
    else ((u16t*)out)[i] = f2bf(val);
}

extern "C" void kernel_launch(void* const* d_in, const int* in_sizes, int n_in,
                              void* d_out, int out_size, void* d_ws, size_t ws_size,
                              hipStream_t stream) {
    const void* t = d_in[0];   // [8,64,256]
    const void* v = d_in[1];   // [8,16384,256]
    char* w = (char*)d_ws;

    u16t*  tnB    = (u16t*)w;                 // 262144 B  [b][t][k] bf16
    float* scores = (float*)(w + 262144);     // 524288 B
    float* Z      = (float*)(w + 786432);
    float* S1     = Z + 512;
    float* S2     = Z + 1024;
    float* c      = Z + 1536;
    float* mnmx   = Z + 2048;                 // 16 floats
    int*   flag   = (int*)(Z + 2064);

    k_sniff<<<1, 64, 0, stream>>>((const u16t*)v, flag);
    k0_zero<<<6, 256, 0, stream>>>(Z);
    k1_tnorm<<<512, 256, 0, stream>>>(t, tnB, flag);
    k_gemm<<<dim3(128, NB), 256, 0, stream>>>(v, tnB, Z, S1, S2, nullptr, nullptr, flag, 0);
    k3_coef<<<NB, 64, 0, stream>>>(Z, S1, S2, c);
    k_gemm<<<dim3(128, NB), 256, 0, stream>>>(v, tnB, Z, S1, S2, c, scores, flag, 1);
    k_mnmx<<<NB, 256, 0, stream>>>(scores, mnmx);
    k5_out<<<512, 256, 0, stream>>>(scores, mnmx, d_out, flag);
}